// Round 8
// baseline (462.995 us; speedup 1.0000x reference)
//
#include <hip/hip_runtime.h>

typedef __attribute__((ext_vector_type(8))) short bf16x8;
typedef __attribute__((ext_vector_type(16))) float f32x16;
typedef __attribute__((ext_vector_type(8))) unsigned short u16x8;
typedef __attribute__((ext_vector_type(4))) unsigned short u16x4;
typedef __attribute__((ext_vector_type(4))) unsigned int u32x4;
typedef __attribute__((ext_vector_type(2))) unsigned int u32x2;

#define NB 8
#define EH 64
#define NS 4096
#define SCALE_L2E 0.1803368801111204f  /* 0.125 * log2(e) */

static __device__ __forceinline__ unsigned short f2bf(float f) {
  union { float f; unsigned int u; } a;
  a.f = f;
  unsigned int u = a.u;
  unsigned int lsb = (u >> 16) & 1u;
  u += 0x7fffu + lsb;  // RNE
  return (unsigned short)(u >> 16);
}

static __device__ __forceinline__ unsigned int cvtpk(float a, float b) {
  unsigned int r;
  asm("v_cvt_pk_bf16_f32 %0, %1, %2" : "=v"(r) : "v"(a), "v"(b));
  return r;
}

// cross-half (lane ^ 32) sum via v_permlane32_swap
static __device__ __forceinline__ float xsum32(float x) {
  u32x2 r = __builtin_amdgcn_permlane32_swap(__float_as_uint(x), __float_as_uint(x), false, false);
  return __uint_as_float(r[0]) + __uint_as_float(r[1]);
}

static __device__ __forceinline__ void gl_lds16(const void* g, void* l) {
  __builtin_amdgcn_global_load_lds(
      (const __attribute__((address_space(1))) unsigned int*)g,
      (__attribute__((address_space(3))) unsigned int*)l, 16, 0, 0);
}

// ---------------- mask dtype detector (wave-parallel): 0 = 1-byte bool, 1 = 4-byte
__global__ void k_detect_mask(const unsigned int* __restrict__ M, int* __restrict__ flag) {
  const int l = threadIdx.x;
  bool ok = true;
  for (int i = l; i < 256; i += 64) {
    const unsigned int w = M[i];
    ok = ok && (w == 0u || w == 1u || w == 0x3F800000u);
  }
  const int all_ok = __all(ok) ? 1 : 0;
  if (l == 0) *flag = all_ok;
}

// ---------------- mask (Nk,Nq) -> bit-packed (Nk/32, Nq) u32: Bits[kw32*NS + q]
__global__ __launch_bounds__(256) void k_mask_bits(const unsigned char* __restrict__ M,
                                                   const int* __restrict__ mflag_p,
                                                   unsigned int* __restrict__ Bits) {
  __shared__ unsigned char Ts[64][80];
  const int q0 = blockIdx.x << 6;
  const int k0 = blockIdx.y << 6;
  const int t = threadIdx.x;
  const int r = t >> 2;
  const int cs = t & 3;
  if (*mflag_p == 0) {
    int4 v = *reinterpret_cast<const int4*>(M + (size_t)(k0 + r) * NS + q0 + cs * 16);
    *reinterpret_cast<int4*>(&Ts[r][cs * 16]) = v;
  } else {
    const unsigned int* Mw = reinterpret_cast<const unsigned int*>(M) + (size_t)(k0 + r) * NS + q0 + cs * 16;
    unsigned char tmp[16];
#pragma unroll
    for (int j = 0; j < 16; ++j) tmp[j] = (unsigned char)(Mw[j] != 0u);
    *reinterpret_cast<int4*>(&Ts[r][cs * 16]) = *reinterpret_cast<const int4*>(tmp);
  }
  __syncthreads();
  const int w = t >> 6, lane = t & 63;
#pragma unroll
  for (int i = 0; i < 16; ++i) {
    const int q = (w << 4) + i;
    unsigned long long bm = __ballot(Ts[lane][q] != 0);
    if (lane == 0) {
      Bits[(size_t)(2 * blockIdx.y) * NS + q0 + q] = (unsigned int)bm;
      Bits[(size_t)(2 * blockIdx.y + 1) * NS + q0 + q] = (unsigned int)(bm >> 32);
    }
  }
}

// ---------------- fused prepass: z=0 K transpose -> (B,N,E) bf16; z=1 V convert
__global__ __launch_bounds__(256) void k_prep(const float* __restrict__ Kf,
                                              const float* __restrict__ Vf,
                                              unsigned short* __restrict__ Kb,
                                              unsigned short* __restrict__ Vb) {
  if (blockIdx.z == 0) {
    __shared__ float T[64][69];
    const int b = blockIdx.y;
    const int n0 = blockIdx.x << 6;
    const float* Xb = Kf + (size_t)b * EH * NS;
    unsigned short* Yb = Kb + (size_t)b * NS * EH;
    const int t = threadIdx.x;
    const int er = t >> 4;
    const int n4 = (t & 15) << 2;
#pragma unroll
    for (int p = 0; p < 4; ++p) {
      const int e = er + (p << 4);
      const float4 v = *reinterpret_cast<const float4*>(Xb + (size_t)e * NS + n0 + n4);
      T[e][n4] = v.x; T[e][n4 + 1] = v.y; T[e][n4 + 2] = v.z; T[e][n4 + 3] = v.w;
    }
    __syncthreads();
    const int n = t >> 2;
    const int e0 = (t & 3) << 4;
    u16x8 o0, o1;
#pragma unroll
    for (int j = 0; j < 8; ++j) o0[j] = f2bf(T[e0 + j][n]);
#pragma unroll
    for (int j = 0; j < 8; ++j) o1[j] = f2bf(T[e0 + 8 + j][n]);
    *reinterpret_cast<u16x8*>(Yb + (size_t)(n0 + n) * EH + e0) = o0;
    *reinterpret_cast<u16x8*>(Yb + (size_t)(n0 + n) * EH + e0 + 8) = o1;
  } else {
    const int id = blockIdx.y * 64 + blockIdx.x;
    const size_t base = (size_t)id * 4096 + threadIdx.x * 4;
#pragma unroll
    for (int i = 0; i < 4; ++i) {
      const float4 v = *reinterpret_cast<const float4*>(Vf + base + i * 1024);
      u16x4 o;
      o[0] = f2bf(v.x); o[1] = f2bf(v.y); o[2] = f2bf(v.z); o[3] = f2bf(v.w);
      *reinterpret_cast<u16x4*>(Vb + base + i * 1024) = o;
    }
  }
}

// ---------------- fused flash attention: split-K x2, single-buffered 32KB LDS,
//                  8 waves/SIMD target, fixed-M softmax
// grid 1024: b = bid&7, qt = (bid>>3)&63, kh = bid>>9
__global__ __launch_bounds__(512, 8) void k_attn6(const unsigned short* __restrict__ Kb,
                                                  const unsigned short* __restrict__ Vb,
                                                  const float* __restrict__ Qf,
                                                  const unsigned int* __restrict__ Bits,
                                                  float* __restrict__ Pw) {
  // pool: [0,16K) K supertile (128k x 64e) | [16K,32K) V supertile (64e x 128k)
  // epilogue alias: M0 [2][3][16][66] f32 (25344B) | Lml [2][3][64] @25344
  __shared__ __align__(16) char pool[32768];

  const int bid = blockIdx.x;
  const int b = bid & 7;
  const int qt = (bid >> 3) & 63;
  const int kh = bid >> 9;            // key half (0/1)
  const int q0 = qt << 6;
  const int t = threadIdx.x;
  const int w = t >> 6;
  const int wq = w & 1;
  const int wk = w >> 1;
  const int l = t & 63;
  const int l32 = l & 31;
  const int hi = l >> 5;
  const int qrow = q0 + (wq << 5) + l32;

  // ---- Q fragments (B operand of S^T = K*Q), scale folded
  bf16x8 qf[4];
  {
    const float* qb = Qf + (size_t)b * EH * NS + qrow;
#pragma unroll
    for (int eb = 0; eb < 4; ++eb)
#pragma unroll
      for (int j = 0; j < 8; ++j)
        qf[eb][j] = (short)f2bf(qb[(size_t)(16 * eb + 8 * hi + j) * NS] * SCALE_L2E);
  }

  // ---- DMA sources (pre-swizzled global, linear LDS dest); kh offsets folded
  const char* kg0 = (const char*)(Kb + ((size_t)b * NS + (size_t)kh * 2048) * EH) +
                    (((size_t)t * 16) ^ (size_t)(((t >> 3) & 7) << 4));
  const char* vg0 = (const char*)(Vb + (size_t)b * EH * NS + (size_t)kh * 2048) +
                    (size_t)(t >> 4) * (NS * 2) +
                    (size_t)((((t & 15) << 4)) ^ (((t >> 4) & 15) << 4));

  // ---- LDS read offsets (same XOR involution)
  const int R = (wk << 5) + l32;
  int koff[4];
#pragma unroll
  for (int eb = 0; eb < 4; ++eb)
    koff[eb] = (R << 7) + (((eb << 5) + (hi << 4)) ^ ((R & 7) << 4));
  int voff[2][2];
#pragma unroll
  for (int vb = 0; vb < 2; ++vb)
#pragma unroll
    for (int kb = 0; kb < 2; ++kb) {
      const int e = (vb << 5) + l32;
      voff[vb][kb] = (e << 8) + (((wk << 6) + (kb << 5) + (hi << 4)) ^ ((e & 15) << 4));
    }

  const unsigned int* mp = Bits + ((size_t)(kh << 6) + wk) * NS + qrow;

  f32x16 acc0, acc1;
#pragma unroll
  for (int r = 0; r < 16; ++r) { acc0[r] = 0.f; acc1[r] = 0.f; }
  float l_r = 0.f;

  for (int kt = 0; kt < 16; ++kt) {
    // ---- stage this supertile (single buffer): 4 DMA + mask load
    gl_lds16(kg0, pool + t * 16);
    gl_lds16(kg0 + 8192, pool + 8192 + t * 16);
    gl_lds16(vg0, pool + 16384 + t * 16);
    gl_lds16(vg0 + (size_t)32 * NS * 2, pool + 16384 + 8192 + t * 16);
    const unsigned int mw = *mp;
    kg0 += 16384; vg0 += 256; mp += (size_t)4 * NS;

    asm volatile("s_waitcnt vmcnt(0)" ::: "memory");
    __builtin_amdgcn_sched_barrier(0);
    __builtin_amdgcn_s_barrier();   // all waves' DMA landed -> LDS consistent

    // ---- S^T init = mask (C-operand): masked entries start at -3e30
    f32x16 s;
#pragma unroll
    for (int r = 0; r < 16; ++r) {
      const int kl = (r & 3) + ((r >> 2) << 3) + (hi << 2);
      s[r] = ((mw >> kl) & 1u) ? -3e30f : 0.0f;
    }

    // ---- S^T[k][q]
    const bf16x8 ka0 = *reinterpret_cast<const bf16x8*>(pool + koff[0]);
    const bf16x8 ka1 = *reinterpret_cast<const bf16x8*>(pool + koff[1]);
    const bf16x8 ka2 = *reinterpret_cast<const bf16x8*>(pool + koff[2]);
    const bf16x8 ka3 = *reinterpret_cast<const bf16x8*>(pool + koff[3]);
    __builtin_amdgcn_s_setprio(1);
    s = __builtin_amdgcn_mfma_f32_32x32x16_bf16(ka0, qf[0], s, 0, 0, 0);
    s = __builtin_amdgcn_mfma_f32_32x32x16_bf16(ka1, qf[1], s, 0, 0, 0);
    s = __builtin_amdgcn_mfma_f32_32x32x16_bf16(ka2, qf[2], s, 0, 0, 0);
    s = __builtin_amdgcn_mfma_f32_32x32x16_bf16(ka3, qf[3], s, 0, 0, 0);
    __builtin_amdgcn_s_setprio(0);

    // ---- p = 2^s (fixed-M; masked -> 0), running denom
#pragma unroll
    for (int r = 0; r < 16; ++r) s[r] = exp2f(s[r]);
    float ts = (((s[0] + s[1]) + (s[2] + s[3])) + ((s[4] + s[5]) + (s[6] + s[7]))) +
               (((s[8] + s[9]) + (s[10] + s[11])) + ((s[12] + s[13]) + (s[14] + s[15])));
    l_r += xsum32(ts);

    // ---- PV: cvt_pk -> permlane32_swap -> MFMAs
    const char* Vt = pool + 16384;
    const bf16x8 va00 = *reinterpret_cast<const bf16x8*>(Vt + voff[0][0]);
    const bf16x8 va01 = *reinterpret_cast<const bf16x8*>(Vt + voff[1][0]);
    const bf16x8 va10 = *reinterpret_cast<const bf16x8*>(Vt + voff[0][1]);
    const bf16x8 va11 = *reinterpret_cast<const bf16x8*>(Vt + voff[1][1]);
#pragma unroll
    for (int kb = 0; kb < 2; ++kb) {
      const unsigned int wA0 = cvtpk(s[8 * kb + 0], s[8 * kb + 1]);
      const unsigned int wA1 = cvtpk(s[8 * kb + 2], s[8 * kb + 3]);
      const unsigned int wB0 = cvtpk(s[8 * kb + 4], s[8 * kb + 5]);
      const unsigned int wB1 = cvtpk(s[8 * kb + 6], s[8 * kb + 7]);
      const u32x2 p02 = __builtin_amdgcn_permlane32_swap(wA0, wB0, false, false);
      const u32x2 p13 = __builtin_amdgcn_permlane32_swap(wA1, wB1, false, false);
      u32x4 pw;
      pw[0] = p02[0];
      pw[1] = p13[0];
      pw[2] = p02[1];
      pw[3] = p13[1];
      const bf16x8 pfrag = __builtin_bit_cast(bf16x8, pw);
      __builtin_amdgcn_s_setprio(1);
      acc0 = __builtin_amdgcn_mfma_f32_32x32x16_bf16(kb ? va10 : va00, pfrag, acc0, 0, 0, 0);
      acc1 = __builtin_amdgcn_mfma_f32_32x32x16_bf16(kb ? va11 : va01, pfrag, acc1, 0, 0, 0);
      __builtin_amdgcn_s_setprio(0);
    }

    __builtin_amdgcn_s_barrier();   // all reads done before next iter's DMA
  }

  // ---- in-block 4-way ksplit merge (two phases to fit 32KB), write partial
  float* M0 = reinterpret_cast<float*>(pool);           // [2][3][16][66]
  float* Lml = reinterpret_cast<float*>(pool + 25344);  // [2][3][64]
  float* pp = Pw + (size_t)((qt << 3) + b) * 2 * 4160 + (size_t)kh * 4160;

  // phase A: acc0 + denom
  if (wk > 0) {
    float* A = M0 + (size_t)(wq * 3 + (wk - 1)) * 16 * 66;
#pragma unroll
    for (int r = 0; r < 16; ++r) A[r * 66 + l] = acc0[r];
    Lml[(wq * 3 + (wk - 1)) * 64 + l] = l_r;
  }
  __syncthreads();
  if (wk == 0) {
    float L = l_r;
#pragma unroll
    for (int s0 = 0; s0 < 3; ++s0) L += Lml[(wq * 3 + s0) * 64 + l];
    if (hi == 0) pp[4096 + (wq << 5) + l32] = L;
#pragma unroll
    for (int r = 0; r < 16; ++r) {
      const int v0 = (r & 3) + ((r >> 2) << 3) + (hi << 2);
      float o = acc0[r];
#pragma unroll
      for (int s0 = 0; s0 < 3; ++s0) o += M0[((size_t)(wq * 3 + s0) * 16 + r) * 66 + l];
      pp[v0 * 64 + (wq << 5) + l32] = o;
    }
  }
  __syncthreads();
  // phase B: acc1
  if (wk > 0) {
    float* A = M0 + (size_t)(wq * 3 + (wk - 1)) * 16 * 66;
#pragma unroll
    for (int r = 0; r < 16; ++r) A[r * 66 + l] = acc1[r];
  }
  __syncthreads();
  if (wk == 0) {
#pragma unroll
    for (int r = 0; r < 16; ++r) {
      const int v0 = (r & 3) + ((r >> 2) << 3) + (hi << 2) + 32;
      float o = acc1[r];
#pragma unroll
      for (int s0 = 0; s0 < 3; ++s0) o += M0[((size_t)(wq * 3 + s0) * 16 + r) * 66 + l];
      pp[v0 * 64 + (wq << 5) + l32] = o;
    }
  }
}

// ---------------- merge the two key-halves and normalize
// grid 512: b = bid&7, qt = bid>>3
__global__ __launch_bounds__(256) void k_merge(const float* __restrict__ Pw,
                                               float* __restrict__ Out) {
  __shared__ float inv[64];
  const int bid = blockIdx.x;
  const int b = bid & 7;
  const int qt = bid >> 3;
  const float* A = Pw + (size_t)((qt << 3) + b) * 2 * 4160;
  const float* B = A + 4160;
  const int t = threadIdx.x;
  if (t < 64) inv[t] = 1.0f / (A[4096 + t] + B[4096 + t]);
  __syncthreads();
  const int v = t >> 2;
  const int qc = (t & 3) << 4;
  const float* ar = A + v * 64 + qc;
  const float* br = B + v * 64 + qc;
  float* ob = Out + ((size_t)b * EH + v) * NS + (qt << 6) + qc;
#pragma unroll
  for (int j = 0; j < 4; ++j) {
    const float4 av = *reinterpret_cast<const float4*>(ar + 4 * j);
    const float4 bv = *reinterpret_cast<const float4*>(br + 4 * j);
    const float4 iv = *reinterpret_cast<const float4*>(&inv[qc + 4 * j]);
    float4 o;
    o.x = (av.x + bv.x) * iv.x;
    o.y = (av.y + bv.y) * iv.y;
    o.z = (av.z + bv.z) * iv.z;
    o.w = (av.w + bv.w) * iv.w;
    *reinterpret_cast<float4*>(ob + 4 * j) = o;
  }
}

extern "C" void kernel_launch(void* const* d_in, const int* in_sizes, int n_in,
                              void* d_out, int out_size, void* d_ws, size_t ws_size,
                              hipStream_t stream) {
  const float* Qf = (const float*)d_in[0];
  const float* Kf = (const float*)d_in[1];
  const float* Vf = (const float*)d_in[2];
  const unsigned char* Mp = (const unsigned char*)d_in[3];
  float* Out = (float*)d_out;

  unsigned short* Kb = (unsigned short*)d_ws;                       // 4 MB
  unsigned short* Vb = Kb + (size_t)NB * NS * EH;                   // 4 MB
  unsigned int* Bits = (unsigned int*)(Vb + (size_t)NB * NS * EH);  // 2 MB
  int* mflag = (int*)(Bits + (size_t)NS * (NS / 32));
  float* Pw = (float*)((char*)d_ws + 10 * 1024 * 1024 + 1024);      // 17.1 MB partials

  k_detect_mask<<<1, 64, 0, stream>>>((const unsigned int*)Mp, mflag);
  k_mask_bits<<<dim3(64, 64), 256, 0, stream>>>(Mp, mflag, Bits);
  k_prep<<<dim3(64, 8, 2), 256, 0, stream>>>(Kf, Vf, Kb, Vb);
  k_attn6<<<dim3(1024), 512, 0, stream>>>(Kb, Vb, Qf, Bits, Pw);
  k_merge<<<dim3(512), 256, 0, stream>>>(Pw, Out);
}

// Round 10
// 105.405 us; speedup vs baseline: 4.3925x; 4.3925x over previous
//
#include <hip/hip_runtime.h>

typedef __attribute__((ext_vector_type(8))) short bf16x8;
typedef __attribute__((ext_vector_type(16))) float f32x16;
typedef __attribute__((ext_vector_type(8))) unsigned short u16x8;
typedef __attribute__((ext_vector_type(4))) unsigned short u16x4;
typedef __attribute__((ext_vector_type(4))) unsigned int u32x4;
typedef __attribute__((ext_vector_type(2))) unsigned int u32x2;

#define NB 8
#define EH 64
#define NS 4096
#define SCALE_L2E 0.1803368801111204f  /* 0.125 * log2(e) */

static __device__ __forceinline__ unsigned short f2bf(float f) {
  union { float f; unsigned int u; } a;
  a.f = f;
  unsigned int u = a.u;
  unsigned int lsb = (u >> 16) & 1u;
  u += 0x7fffu + lsb;  // RNE
  return (unsigned short)(u >> 16);
}

static __device__ __forceinline__ unsigned int cvtpk(float a, float b) {
  unsigned int r;
  asm("v_cvt_pk_bf16_f32 %0, %1, %2" : "=v"(r) : "v"(a), "v"(b));
  return r;
}

// cross-half (lane ^ 32) sum via v_permlane32_swap
static __device__ __forceinline__ float xsum32(float x) {
  u32x2 r = __builtin_amdgcn_permlane32_swap(__float_as_uint(x), __float_as_uint(x), false, false);
  return __uint_as_float(r[0]) + __uint_as_float(r[1]);
}

static __device__ __forceinline__ void gl_lds16(const void* g, void* l) {
  __builtin_amdgcn_global_load_lds(
      (const __attribute__((address_space(1))) unsigned int*)g,
      (__attribute__((address_space(3))) unsigned int*)l, 16, 0, 0);
}

// ---------------- mask dtype detector (wave-parallel): 0 = 1-byte bool, 1 = 4-byte
__global__ void k_detect_mask(const unsigned int* __restrict__ M, int* __restrict__ flag) {
  const int l = threadIdx.x;
  bool ok = true;
  for (int i = l; i < 256; i += 64) {
    const unsigned int w = M[i];
    ok = ok && (w == 0u || w == 1u || w == 0x3F800000u);
  }
  const int all_ok = __all(ok) ? 1 : 0;
  if (l == 0) *flag = all_ok;
}

// ---------------- mask (Nk,Nq) -> bit-packed (Nk/32, Nq) u32: Bits[kw32*NS + q]
__global__ __launch_bounds__(256) void k_mask_bits(const unsigned char* __restrict__ M,
                                                   const int* __restrict__ mflag_p,
                                                   unsigned int* __restrict__ Bits) {
  __shared__ unsigned char Ts[64][80];
  const int q0 = blockIdx.x << 6;
  const int k0 = blockIdx.y << 6;
  const int t = threadIdx.x;
  const int r = t >> 2;
  const int cs = t & 3;
  if (*mflag_p == 0) {
    int4 v = *reinterpret_cast<const int4*>(M + (size_t)(k0 + r) * NS + q0 + cs * 16);
    *reinterpret_cast<int4*>(&Ts[r][cs * 16]) = v;
  } else {
    const unsigned int* Mw = reinterpret_cast<const unsigned int*>(M) + (size_t)(k0 + r) * NS + q0 + cs * 16;
    unsigned char tmp[16];
#pragma unroll
    for (int j = 0; j < 16; ++j) tmp[j] = (unsigned char)(Mw[j] != 0u);
    *reinterpret_cast<int4*>(&Ts[r][cs * 16]) = *reinterpret_cast<const int4*>(tmp);
  }
  __syncthreads();
  const int w = t >> 6, lane = t & 63;
#pragma unroll
  for (int i = 0; i < 16; ++i) {
    const int q = (w << 4) + i;
    unsigned long long bm = __ballot(Ts[lane][q] != 0);
    if (lane == 0) {
      Bits[(size_t)(2 * blockIdx.y) * NS + q0 + q] = (unsigned int)bm;
      Bits[(size_t)(2 * blockIdx.y + 1) * NS + q0 + q] = (unsigned int)(bm >> 32);
    }
  }
}

// ---------------- fused prepass: z=0 K transpose -> (B,N,E) bf16; z=1 V convert
__global__ __launch_bounds__(256) void k_prep(const float* __restrict__ Kf,
                                              const float* __restrict__ Vf,
                                              unsigned short* __restrict__ Kb,
                                              unsigned short* __restrict__ Vb) {
  if (blockIdx.z == 0) {
    __shared__ float T[64][69];
    const int b = blockIdx.y;
    const int n0 = blockIdx.x << 6;
    const float* Xb = Kf + (size_t)b * EH * NS;
    unsigned short* Yb = Kb + (size_t)b * NS * EH;
    const int t = threadIdx.x;
    const int er = t >> 4;
    const int n4 = (t & 15) << 2;
#pragma unroll
    for (int p = 0; p < 4; ++p) {
      const int e = er + (p << 4);
      const float4 v = *reinterpret_cast<const float4*>(Xb + (size_t)e * NS + n0 + n4);
      T[e][n4] = v.x; T[e][n4 + 1] = v.y; T[e][n4 + 2] = v.z; T[e][n4 + 3] = v.w;
    }
    __syncthreads();
    const int n = t >> 2;
    const int e0 = (t & 3) << 4;
    u16x8 o0, o1;
#pragma unroll
    for (int j = 0; j < 8; ++j) o0[j] = f2bf(T[e0 + j][n]);
#pragma unroll
    for (int j = 0; j < 8; ++j) o1[j] = f2bf(T[e0 + 8 + j][n]);
    *reinterpret_cast<u16x8*>(Yb + (size_t)(n0 + n) * EH + e0) = o0;
    *reinterpret_cast<u16x8*>(Yb + (size_t)(n0 + n) * EH + e0 + 8) = o1;
  } else {
    const int id = blockIdx.y * 64 + blockIdx.x;
    const size_t base = (size_t)id * 4096 + threadIdx.x * 4;
#pragma unroll
    for (int i = 0; i < 4; ++i) {
      const float4 v = *reinterpret_cast<const float4*>(Vf + base + i * 1024);
      u16x4 o;
      o[0] = f2bf(v.x); o[1] = f2bf(v.y); o[2] = f2bf(v.z); o[3] = f2bf(v.w);
      *reinterpret_cast<u16x4*>(Vb + base + i * 1024) = o;
    }
  }
}

// ---------------- fused flash attention: split-K x2, single-buffered 32KB LDS,
//                  fixed-M softmax; launch_bounds(512,4) -> natural ~64 VGPR
// grid 1024: b = bid&7, qt = (bid>>3)&63, kh = bid>>9
__global__ __launch_bounds__(512, 4) void k_attn6(const unsigned short* __restrict__ Kb,
                                                  const unsigned short* __restrict__ Vb,
                                                  const float* __restrict__ Qf,
                                                  const unsigned int* __restrict__ Bits,
                                                  float* __restrict__ Pw) {
  // pool: [0,16K) K supertile (128k x 64e) | [16K,32K) V supertile (64e x 128k)
  // epilogue alias: M0 [2][3][16][66] f32 (25344B) | Lml [2][3][64] @25344
  __shared__ __align__(16) char pool[32768];

  const int bid = blockIdx.x;
  const int b = bid & 7;
  const int qt = (bid >> 3) & 63;
  const int kh = bid >> 9;            // key half (0/1)
  const int q0 = qt << 6;
  const int t = threadIdx.x;
  const int w = t >> 6;
  const int wq = w & 1;
  const int wk = w >> 1;
  const int l = t & 63;
  const int l32 = l & 31;
  const int hi = l >> 5;
  const int qrow = q0 + (wq << 5) + l32;

  // ---- Q fragments (B operand of S^T = K*Q), scale folded
  bf16x8 qf[4];
  {
    const float* qb = Qf + (size_t)b * EH * NS + qrow;
#pragma unroll
    for (int eb = 0; eb < 4; ++eb)
#pragma unroll
      for (int j = 0; j < 8; ++j)
        qf[eb][j] = (short)f2bf(qb[(size_t)(16 * eb + 8 * hi + j) * NS] * SCALE_L2E);
  }

  // ---- DMA sources (pre-swizzled global, linear LDS dest); kh offsets folded
  const char* kg0 = (const char*)(Kb + ((size_t)b * NS + (size_t)kh * 2048) * EH) +
                    (((size_t)t * 16) ^ (size_t)(((t >> 3) & 7) << 4));
  const char* vg0 = (const char*)(Vb + (size_t)b * EH * NS + (size_t)kh * 2048) +
                    (size_t)(t >> 4) * (NS * 2) +
                    (size_t)((((t & 15) << 4)) ^ (((t >> 4) & 15) << 4));

  // ---- LDS read offsets (same XOR involution)
  const int R = (wk << 5) + l32;
  int koff[4];
#pragma unroll
  for (int eb = 0; eb < 4; ++eb)
    koff[eb] = (R << 7) + (((eb << 5) + (hi << 4)) ^ ((R & 7) << 4));
  int voff[2][2];
#pragma unroll
  for (int vb = 0; vb < 2; ++vb)
#pragma unroll
    for (int kb = 0; kb < 2; ++kb) {
      const int e = (vb << 5) + l32;
      voff[vb][kb] = (e << 8) + (((wk << 6) + (kb << 5) + (hi << 4)) ^ ((e & 15) << 4));
    }

  const unsigned int* mp = Bits + ((size_t)(kh << 6) + wk) * NS + qrow;

  f32x16 acc0, acc1;
#pragma unroll
  for (int r = 0; r < 16; ++r) { acc0[r] = 0.f; acc1[r] = 0.f; }
  float l_r = 0.f;

  for (int kt = 0; kt < 16; ++kt) {
    // ---- stage this supertile (single buffer): 4 DMA + mask load
    gl_lds16(kg0, pool + t * 16);
    gl_lds16(kg0 + 8192, pool + 8192 + t * 16);
    gl_lds16(vg0, pool + 16384 + t * 16);
    gl_lds16(vg0 + (size_t)32 * NS * 2, pool + 16384 + 8192 + t * 16);
    const unsigned int mw = *mp;
    kg0 += 16384; vg0 += 256; mp += (size_t)4 * NS;

    asm volatile("s_waitcnt vmcnt(0)" ::: "memory");
    __builtin_amdgcn_sched_barrier(0);
    __builtin_amdgcn_s_barrier();   // all waves' DMA landed -> LDS consistent

    // ---- S^T init = mask (C-operand): masked entries start at -inf (3-op/elem)
    const unsigned int mwh = mw >> (hi << 2);
    f32x16 s;
#pragma unroll
    for (int r = 0; r < 16; ++r) {
      const int kl = (r & 3) + ((r >> 2) << 3);  // compile-time per r
      s[r] = __int_as_float(((int)(mwh << (31 - kl)) >> 31) & 0xFF800000);
    }

    // ---- S^T[k][q]
    const bf16x8 ka0 = *reinterpret_cast<const bf16x8*>(pool + koff[0]);
    const bf16x8 ka1 = *reinterpret_cast<const bf16x8*>(pool + koff[1]);
    const bf16x8 ka2 = *reinterpret_cast<const bf16x8*>(pool + koff[2]);
    const bf16x8 ka3 = *reinterpret_cast<const bf16x8*>(pool + koff[3]);
    __builtin_amdgcn_s_setprio(1);
    s = __builtin_amdgcn_mfma_f32_32x32x16_bf16(ka0, qf[0], s, 0, 0, 0);
    s = __builtin_amdgcn_mfma_f32_32x32x16_bf16(ka1, qf[1], s, 0, 0, 0);
    s = __builtin_amdgcn_mfma_f32_32x32x16_bf16(ka2, qf[2], s, 0, 0, 0);
    s = __builtin_amdgcn_mfma_f32_32x32x16_bf16(ka3, qf[3], s, 0, 0, 0);
    __builtin_amdgcn_s_setprio(0);

    // ---- p = 2^s (fixed-M; masked -> exp2(-inf)=0); compiler-handled TRANS hazard
#pragma unroll
    for (int r = 0; r < 16; ++r) s[r] = exp2f(s[r]);
    l_r += (((s[0] + s[1]) + (s[2] + s[3])) + ((s[4] + s[5]) + (s[6] + s[7]))) +
           (((s[8] + s[9]) + (s[10] + s[11])) + ((s[12] + s[13]) + (s[14] + s[15])));

    // ---- PV: cvt_pk -> permlane32_swap -> MFMAs
    const char* Vt = pool + 16384;
    const bf16x8 va00 = *reinterpret_cast<const bf16x8*>(Vt + voff[0][0]);
    const bf16x8 va01 = *reinterpret_cast<const bf16x8*>(Vt + voff[1][0]);
    const bf16x8 va10 = *reinterpret_cast<const bf16x8*>(Vt + voff[0][1]);
    const bf16x8 va11 = *reinterpret_cast<const bf16x8*>(Vt + voff[1][1]);
#pragma unroll
    for (int kb = 0; kb < 2; ++kb) {
      const unsigned int wA0 = cvtpk(s[8 * kb + 0], s[8 * kb + 1]);
      const unsigned int wA1 = cvtpk(s[8 * kb + 2], s[8 * kb + 3]);
      const unsigned int wB0 = cvtpk(s[8 * kb + 4], s[8 * kb + 5]);
      const unsigned int wB1 = cvtpk(s[8 * kb + 6], s[8 * kb + 7]);
      const u32x2 p02 = __builtin_amdgcn_permlane32_swap(wA0, wB0, false, false);
      const u32x2 p13 = __builtin_amdgcn_permlane32_swap(wA1, wB1, false, false);
      u32x4 pw;
      pw[0] = p02[0];
      pw[1] = p13[0];
      pw[2] = p02[1];
      pw[3] = p13[1];
      const bf16x8 pfrag = __builtin_bit_cast(bf16x8, pw);
      __builtin_amdgcn_s_setprio(1);
      acc0 = __builtin_amdgcn_mfma_f32_32x32x16_bf16(kb ? va10 : va00, pfrag, acc0, 0, 0, 0);
      acc1 = __builtin_amdgcn_mfma_f32_32x32x16_bf16(kb ? va11 : va01, pfrag, acc1, 0, 0, 0);
      __builtin_amdgcn_s_setprio(0);
    }

    __builtin_amdgcn_s_barrier();   // all reads done before next iter's DMA
  }

  // ---- finalize denom across lane halves (deferred from loop)
  l_r = xsum32(l_r);

  // ---- in-block 4-way ksplit merge (two phases to fit 32KB), write partial
  float* M0 = reinterpret_cast<float*>(pool);           // [2][3][16][66]
  float* Lml = reinterpret_cast<float*>(pool + 25344);  // [2][3][64]
  float* pp = Pw + (size_t)((qt << 3) + b) * 2 * 4160 + (size_t)kh * 4160;

  // phase A: acc0 + denom
  if (wk > 0) {
    float* A = M0 + (size_t)(wq * 3 + (wk - 1)) * 16 * 66;
#pragma unroll
    for (int r = 0; r < 16; ++r) A[r * 66 + l] = acc0[r];
    Lml[(wq * 3 + (wk - 1)) * 64 + l] = l_r;
  }
  __syncthreads();
  if (wk == 0) {
    float L = l_r;
#pragma unroll
    for (int s0 = 0; s0 < 3; ++s0) L += Lml[(wq * 3 + s0) * 64 + l];
    if (hi == 0) pp[4096 + (wq << 5) + l32] = L;
#pragma unroll
    for (int r = 0; r < 16; ++r) {
      const int v0 = (r & 3) + ((r >> 2) << 3) + (hi << 2);
      float o = acc0[r];
#pragma unroll
      for (int s0 = 0; s0 < 3; ++s0) o += M0[((size_t)(wq * 3 + s0) * 16 + r) * 66 + l];
      pp[v0 * 64 + (wq << 5) + l32] = o;
    }
  }
  __syncthreads();
  // phase B: acc1
  if (wk > 0) {
    float* A = M0 + (size_t)(wq * 3 + (wk - 1)) * 16 * 66;
#pragma unroll
    for (int r = 0; r < 16; ++r) A[r * 66 + l] = acc1[r];
  }
  __syncthreads();
  if (wk == 0) {
#pragma unroll
    for (int r = 0; r < 16; ++r) {
      const int v0 = (r & 3) + ((r >> 2) << 3) + (hi << 2) + 32;
      float o = acc1[r];
#pragma unroll
      for (int s0 = 0; s0 < 3; ++s0) o += M0[((size_t)(wq * 3 + s0) * 16 + r) * 66 + l];
      pp[v0 * 64 + (wq << 5) + l32] = o;
    }
  }
}

// ---------------- merge the two key-halves and normalize
// grid 512: b = bid&7, qt = bid>>3
__global__ __launch_bounds__(256) void k_merge(const float* __restrict__ Pw,
                                               float* __restrict__ Out) {
  __shared__ float inv[64];
  const int bid = blockIdx.x;
  const int b = bid & 7;
  const int qt = bid >> 3;
  const float* A = Pw + (size_t)((qt << 3) + b) * 2 * 4160;
  const float* B = A + 4160;
  const int t = threadIdx.x;
  if (t < 64) inv[t] = 1.0f / (A[4096 + t] + B[4096 + t]);
  __syncthreads();
  const int v = t >> 2;
  const int qc = (t & 3) << 4;
  const float* ar = A + v * 64 + qc;
  const float* br = B + v * 64 + qc;
  float* ob = Out + ((size_t)b * EH + v) * NS + (qt << 6) + qc;
#pragma unroll
  for (int j = 0; j < 4; ++j) {
    const float4 av = *reinterpret_cast<const float4*>(ar + 4 * j);
    const float4 bv = *reinterpret_cast<const float4*>(br + 4 * j);
    const float4 iv = *reinterpret_cast<const float4*>(&inv[qc + 4 * j]);
    float4 o;
    o.x = (av.x + bv.x) * iv.x;
    o.y = (av.y + bv.y) * iv.y;
    o.z = (av.z + bv.z) * iv.z;
    o.w = (av.w + bv.w) * iv.w;
    *reinterpret_cast<float4*>(ob + 4 * j) = o;
  }
}

extern "C" void kernel_launch(void* const* d_in, const int* in_sizes, int n_in,
                              void* d_out, int out_size, void* d_ws, size_t ws_size,
                              hipStream_t stream) {
  const float* Qf = (const float*)d_in[0];
  const float* Kf = (const float*)d_in[1];
  const float* Vf = (const float*)d_in[2];
  const unsigned char* Mp = (const unsigned char*)d_in[3];
  float* Out = (float*)d_out;

  unsigned short* Kb = (unsigned short*)d_ws;                       // 4 MB
  unsigned short* Vb = Kb + (size_t)NB * NS * EH;                   // 4 MB
  unsigned int* Bits = (unsigned int*)(Vb + (size_t)NB * NS * EH);  // 2 MB
  int* mflag = (int*)(Bits + (size_t)NS * (NS / 32));
  float* Pw = (float*)((char*)d_ws + 10 * 1024 * 1024 + 1024);      // 17.1 MB partials

  k_detect_mask<<<1, 64, 0, stream>>>((const unsigned int*)Mp, mflag);
  k_mask_bits<<<dim3(64, 64), 256, 0, stream>>>(Mp, mflag, Bits);
  k_prep<<<dim3(64, 8, 2), 256, 0, stream>>>(Kf, Vf, Kb, Vb);
  k_attn6<<<dim3(1024), 512, 0, stream>>>(Kb, Vb, Qf, Bits, Pw);
  k_merge<<<dim3(512), 256, 0, stream>>>(Pw, Out);
}

// Round 11
// 102.537 us; speedup vs baseline: 4.5154x; 1.0280x over previous
//
#include <hip/hip_runtime.h>

typedef __attribute__((ext_vector_type(8))) short bf16x8;
typedef __attribute__((ext_vector_type(16))) float f32x16;
typedef __attribute__((ext_vector_type(8))) unsigned short u16x8;
typedef __attribute__((ext_vector_type(4))) unsigned short u16x4;
typedef __attribute__((ext_vector_type(4))) unsigned int u32x4;
typedef __attribute__((ext_vector_type(2))) unsigned int u32x2;

#define NB 8
#define EH 64
#define NS 4096
#define SCALE_L2E 0.1803368801111204f  /* 0.125 * log2(e) */

static __device__ __forceinline__ unsigned short f2bf(float f) {
  union { float f; unsigned int u; } a;
  a.f = f;
  unsigned int u = a.u;
  unsigned int lsb = (u >> 16) & 1u;
  u += 0x7fffu + lsb;  // RNE
  return (unsigned short)(u >> 16);
}

static __device__ __forceinline__ unsigned int cvtpk(float a, float b) {
  unsigned int r;
  asm("v_cvt_pk_bf16_f32 %0, %1, %2" : "=v"(r) : "v"(a), "v"(b));
  return r;
}

// cross-half (lane ^ 32) sum via v_permlane32_swap
static __device__ __forceinline__ float xsum32(float x) {
  u32x2 r = __builtin_amdgcn_permlane32_swap(__float_as_uint(x), __float_as_uint(x), false, false);
  return __uint_as_float(r[0]) + __uint_as_float(r[1]);
}

static __device__ __forceinline__ void gl_lds16(const void* g, void* l) {
  __builtin_amdgcn_global_load_lds(
      (const __attribute__((address_space(1))) unsigned int*)g,
      (__attribute__((address_space(3))) unsigned int*)l, 16, 0, 0);
}

// ---------------- fused prepass (one launch):
//   bid <  4096 : mask (Nk,Nq) -> bit-packed (Nk/32, Nq), with inline dtype detect
//   4096..4607  : K transpose (B,E,N) f32 -> (B,N,E) bf16
//   4608..5119  : V convert   (B,E,N) f32 -> bf16 (layout kept)
__global__ __launch_bounds__(256) void k_pre(const float* __restrict__ Kf,
                                             const float* __restrict__ Vf,
                                             const unsigned char* __restrict__ Mp,
                                             unsigned short* __restrict__ Kb,
                                             unsigned short* __restrict__ Vb,
                                             unsigned int* __restrict__ Bits) {
  const int bid = blockIdx.x;
  const int t = threadIdx.x;
  if (bid < 4096) {
    __shared__ unsigned char Ts[64][80];
    __shared__ int sfl;
    const int q0 = (bid & 63) << 6;
    const int ky = bid >> 6;
    const int k0 = ky << 6;
    if (t == 0) sfl = 1;
    __syncthreads();
    {
      const unsigned int w0 = reinterpret_cast<const unsigned int*>(Mp)[t];
      if (!(w0 == 0u || w0 == 1u || w0 == 0x3F800000u)) sfl = 0;  // benign race
    }
    __syncthreads();
    const int wide = sfl;
    const int r = t >> 2, cs = t & 3;
    if (!wide) {
      int4 v = *reinterpret_cast<const int4*>(Mp + (size_t)(k0 + r) * NS + q0 + cs * 16);
      *reinterpret_cast<int4*>(&Ts[r][cs * 16]) = v;
    } else {
      const unsigned int* Mw =
          reinterpret_cast<const unsigned int*>(Mp) + (size_t)(k0 + r) * NS + q0 + cs * 16;
      unsigned char tmp[16];
#pragma unroll
      for (int j = 0; j < 16; ++j) tmp[j] = (unsigned char)(Mw[j] != 0u);
      *reinterpret_cast<int4*>(&Ts[r][cs * 16]) = *reinterpret_cast<const int4*>(tmp);
    }
    __syncthreads();
    const int w = t >> 6, lane = t & 63;
#pragma unroll
    for (int i = 0; i < 16; ++i) {
      const int q = (w << 4) + i;
      unsigned long long bm = __ballot(Ts[lane][q] != 0);
      if (lane == 0) {
        Bits[(size_t)(2 * ky) * NS + q0 + q] = (unsigned int)bm;
        Bits[(size_t)(2 * ky + 1) * NS + q0 + q] = (unsigned int)(bm >> 32);
      }
    }
  } else if (bid < 4608) {
    __shared__ float T[64][69];
    const int id = bid - 4096;
    const int b = id >> 6;
    const int n0 = (id & 63) << 6;
    const float* Xb = Kf + (size_t)b * EH * NS;
    unsigned short* Yb = Kb + (size_t)b * NS * EH;
    const int er = t >> 4;
    const int n4 = (t & 15) << 2;
#pragma unroll
    for (int p = 0; p < 4; ++p) {
      const int e = er + (p << 4);
      const float4 v = *reinterpret_cast<const float4*>(Xb + (size_t)e * NS + n0 + n4);
      T[e][n4] = v.x; T[e][n4 + 1] = v.y; T[e][n4 + 2] = v.z; T[e][n4 + 3] = v.w;
    }
    __syncthreads();
    const int n = t >> 2;
    const int e0 = (t & 3) << 4;
    u16x8 o0, o1;
#pragma unroll
    for (int j = 0; j < 8; ++j) o0[j] = f2bf(T[e0 + j][n]);
#pragma unroll
    for (int j = 0; j < 8; ++j) o1[j] = f2bf(T[e0 + 8 + j][n]);
    *reinterpret_cast<u16x8*>(Yb + (size_t)(n0 + n) * EH + e0) = o0;
    *reinterpret_cast<u16x8*>(Yb + (size_t)(n0 + n) * EH + e0 + 8) = o1;
  } else {
    const int id = bid - 4608;
    const size_t base = (size_t)id * 4096 + t * 4;
#pragma unroll
    for (int i = 0; i < 4; ++i) {
      const float4 v = *reinterpret_cast<const float4*>(Vf + base + i * 1024);
      u16x4 o;
      o[0] = f2bf(v.x); o[1] = f2bf(v.y); o[2] = f2bf(v.z); o[3] = f2bf(v.w);
      *reinterpret_cast<u16x4*>(Vb + base + i * 1024) = o;
    }
  }
}

// ---------------- fused flash attention: K LDS-dbuf (DMA), V direct-from-L2,
//                  fixed-M softmax, 4 waves/block (wk-split), 32 q/block
// grid 1024: b = bid&7, qtile = bid>>3
__global__ __launch_bounds__(256, 4) void k_attn7(const unsigned short* __restrict__ Kb,
                                                  const unsigned short* __restrict__ Vb,
                                                  const float* __restrict__ Qf,
                                                  const unsigned int* __restrict__ Bits,
                                                  float* __restrict__ Out) {
  // pool: [0,16K) K buf0 | [16K,32K) K buf1 (128 keys x 64 e bf16 each)
  // epilogue alias: MAcc [3][64][33] f32 (25344 B) | Lml [3][32] @25344
  __shared__ __align__(16) char pool[32768];

  const int bid = blockIdx.x;
  const int b = bid & 7;              // batch -> XCD (L2 locality)
  const int q0 = (bid >> 3) << 5;     // 32 q per block
  const int t = threadIdx.x;
  const int wk = t >> 6;              // 4 key splits of 32
  const int l = t & 63;
  const int l32 = l & 31;
  const int hi = l >> 5;
  const int qrow = q0 + l32;

  // ---- Q fragments (B operand of S^T = K*Q), scale folded
  bf16x8 qf[4];
  {
    const float* qb = Qf + (size_t)b * EH * NS + qrow;
#pragma unroll
    for (int eb = 0; eb < 4; ++eb)
#pragma unroll
      for (int j = 0; j < 8; ++j)
        qf[eb][j] = (short)f2bf(qb[(size_t)(16 * eb + 8 * hi + j) * NS] * SCALE_L2E);
  }

  // ---- K DMA source (pre-swizzled global, linear LDS dest); 4 chunks/thread
  const char* kg = (const char*)(Kb + (size_t)b * NS * EH) +
                   (((size_t)t * 16) ^ (size_t)(((t >> 3) & 7) << 4));

  // ---- K LDS read offsets (same XOR involution)
  const int R = (wk << 5) + l32;  // key row in 128-key supertile
  int koff[4];
#pragma unroll
  for (int eb = 0; eb < 4; ++eb)
    koff[eb] = (R << 7) + (((eb << 5) + (hi << 4)) ^ ((R & 7) << 4));

  // ---- V direct-global fragment pointers: e = l32 (+32), col = wk*32 + kb*16 + hi*8
  const unsigned short* vb0 = Vb + ((size_t)b * EH + l32) * NS + (wk << 5) + (hi << 3);
  const unsigned short* vb1 = vb0 + (size_t)32 * NS;

  const unsigned int* mp = Bits + (size_t)wk * NS + qrow;  // word kt*4+wk

  f32x16 acc0, acc1;
#pragma unroll
  for (int r = 0; r < 16; ++r) { acc0[r] = 0.f; acc1[r] = 0.f; }
  float l_r = 0.f;

  // ---- prologue: stage K supertile 0
#pragma unroll
  for (int i = 0; i < 4; ++i) gl_lds16(kg + i * 4096, pool + i * 4096 + t * 16);
  unsigned int mw = mp[0];
  __syncthreads();

  unsigned int mw_n = 0;
  for (int kt = 0; kt < 32; ++kt) {
    const int cur = kt & 1;
    // next-supertile K DMA (completes by this iteration's end barrier)
    if (kt < 31) {
      const char* kgn = kg + (size_t)(kt + 1) * 16384;
      char* Kn = pool + ((cur ^ 1) << 14);
#pragma unroll
      for (int i = 0; i < 4; ++i) gl_lds16(kgn + i * 4096, Kn + i * 4096 + t * 16);
      mw_n = mp[(size_t)(kt + 1) * 4 * NS];
    }

    // current V fragments: issued early, consumed after QK+exp (~500 cyc later)
    const unsigned short* vp0 = vb0 + kt * 128;
    const unsigned short* vp1 = vb1 + kt * 128;
    const bf16x8 va00 = *reinterpret_cast<const bf16x8*>(vp0);
    const bf16x8 va01 = *reinterpret_cast<const bf16x8*>(vp1);
    const bf16x8 va10 = *reinterpret_cast<const bf16x8*>(vp0 + 16);
    const bf16x8 va11 = *reinterpret_cast<const bf16x8*>(vp1 + 16);

    // ---- S^T init = mask (C-operand): masked entries start at -inf
    const unsigned int mwh = mw >> (hi << 2);
    f32x16 s;
#pragma unroll
    for (int r = 0; r < 16; ++r) {
      const int kl = (r & 3) + ((r >> 2) << 3);  // compile-time per r
      s[r] = __int_as_float(((int)(mwh << (31 - kl)) >> 31) & 0xFF800000);
    }

    // ---- S^T[k][q]
    const char* Kt = pool + (cur << 14);
    const bf16x8 ka0 = *reinterpret_cast<const bf16x8*>(Kt + koff[0]);
    const bf16x8 ka1 = *reinterpret_cast<const bf16x8*>(Kt + koff[1]);
    const bf16x8 ka2 = *reinterpret_cast<const bf16x8*>(Kt + koff[2]);
    const bf16x8 ka3 = *reinterpret_cast<const bf16x8*>(Kt + koff[3]);
    __builtin_amdgcn_s_setprio(1);
    s = __builtin_amdgcn_mfma_f32_32x32x16_bf16(ka0, qf[0], s, 0, 0, 0);
    s = __builtin_amdgcn_mfma_f32_32x32x16_bf16(ka1, qf[1], s, 0, 0, 0);
    s = __builtin_amdgcn_mfma_f32_32x32x16_bf16(ka2, qf[2], s, 0, 0, 0);
    s = __builtin_amdgcn_mfma_f32_32x32x16_bf16(ka3, qf[3], s, 0, 0, 0);
    __builtin_amdgcn_s_setprio(0);

    // ---- p = 2^s (fixed-M; masked -> exp2(-inf)=0), deferred denom
#pragma unroll
    for (int r = 0; r < 16; ++r) s[r] = exp2f(s[r]);
    l_r += (((s[0] + s[1]) + (s[2] + s[3])) + ((s[4] + s[5]) + (s[6] + s[7]))) +
           (((s[8] + s[9]) + (s[10] + s[11])) + ((s[12] + s[13]) + (s[14] + s[15])));

    // ---- PV: cvt_pk -> permlane32_swap -> MFMAs
#pragma unroll
    for (int kb = 0; kb < 2; ++kb) {
      const unsigned int wA0 = cvtpk(s[8 * kb + 0], s[8 * kb + 1]);
      const unsigned int wA1 = cvtpk(s[8 * kb + 2], s[8 * kb + 3]);
      const unsigned int wB0 = cvtpk(s[8 * kb + 4], s[8 * kb + 5]);
      const unsigned int wB1 = cvtpk(s[8 * kb + 6], s[8 * kb + 7]);
      const u32x2 p02 = __builtin_amdgcn_permlane32_swap(wA0, wB0, false, false);
      const u32x2 p13 = __builtin_amdgcn_permlane32_swap(wA1, wB1, false, false);
      u32x4 pw;
      pw[0] = p02[0];
      pw[1] = p13[0];
      pw[2] = p02[1];
      pw[3] = p13[1];
      const bf16x8 pfrag = __builtin_bit_cast(bf16x8, pw);
      __builtin_amdgcn_s_setprio(1);
      acc0 = __builtin_amdgcn_mfma_f32_32x32x16_bf16(kb ? va10 : va00, pfrag, acc0, 0, 0, 0);
      acc1 = __builtin_amdgcn_mfma_f32_32x32x16_bf16(kb ? va11 : va01, pfrag, acc1, 0, 0, 0);
      __builtin_amdgcn_s_setprio(0);
    }

    mw = mw_n;
    __syncthreads();  // drains K DMA; next buffer ready
  }

  // ---- finalize denom across lane halves (deferred from loop)
  l_r = xsum32(l_r);

  // ---- 4-way wk merge through LDS (plain sums; fixed-M), write Out directly
  float* MAcc = reinterpret_cast<float*>(pool);          // [3][64][33]
  float* Lml = reinterpret_cast<float*>(pool + 25344);   // [3][32]
  if (wk > 0) {
    float* A = MAcc + (size_t)(wk - 1) * 64 * 33;
#pragma unroll
    for (int r = 0; r < 16; ++r) {
      const int v0 = (r & 3) + ((r >> 2) << 3) + (hi << 2);
      A[v0 * 33 + l32] = acc0[r];
      A[(v0 + 32) * 33 + l32] = acc1[r];
    }
    if (l < 32) Lml[(wk - 1) * 32 + l32] = l_r;
  }
  __syncthreads();
  if (wk == 0) {
    const float L = l_r + Lml[l32] + Lml[32 + l32] + Lml[64 + l32];
    const float inv = 1.0f / L;
    float* ob = Out + (size_t)b * EH * NS + qrow;
#pragma unroll
    for (int r = 0; r < 16; ++r) {
      const int v0 = (r & 3) + ((r >> 2) << 3) + (hi << 2);
      float o0 = acc0[r];
      float o1 = acc1[r];
#pragma unroll
      for (int s0 = 0; s0 < 3; ++s0) {
        o0 += MAcc[(size_t)s0 * 64 * 33 + v0 * 33 + l32];
        o1 += MAcc[(size_t)s0 * 64 * 33 + (v0 + 32) * 33 + l32];
      }
      ob[(size_t)v0 * NS] = o0 * inv;
      ob[(size_t)(v0 + 32) * NS] = o1 * inv;
    }
  }
}

extern "C" void kernel_launch(void* const* d_in, const int* in_sizes, int n_in,
                              void* d_out, int out_size, void* d_ws, size_t ws_size,
                              hipStream_t stream) {
  const float* Qf = (const float*)d_in[0];
  const float* Kf = (const float*)d_in[1];
  const float* Vf = (const float*)d_in[2];
  const unsigned char* Mp = (const unsigned char*)d_in[3];
  float* Out = (float*)d_out;

  unsigned short* Kb = (unsigned short*)d_ws;                       // 4 MB
  unsigned short* Vb = Kb + (size_t)NB * NS * EH;                   // 4 MB
  unsigned int* Bits = (unsigned int*)(Vb + (size_t)NB * NS * EH);  // 2 MB

  k_pre<<<dim3(5120), 256, 0, stream>>>(Kf, Vf, Mp, Kb, Vb, Bits);
  k_attn7<<<dim3(1024), 256, 0, stream>>>(Kb, Vb, Qf, Bits, Out);
}

// Round 12
// 90.451 us; speedup vs baseline: 5.1187x; 1.1336x over previous
//
#include <hip/hip_runtime.h>

typedef __attribute__((ext_vector_type(8))) short bf16x8;
typedef __attribute__((ext_vector_type(16))) float f32x16;
typedef __attribute__((ext_vector_type(8))) unsigned short u16x8;
typedef __attribute__((ext_vector_type(4))) unsigned short u16x4;
typedef __attribute__((ext_vector_type(4))) unsigned int u32x4;
typedef __attribute__((ext_vector_type(2))) unsigned int u32x2;

#define NB 8
#define EH 64
#define NS 4096
#define SCALE_L2E 0.1803368801111204f  /* 0.125 * log2(e) */
#define PBLK 8320                      /* 64*128 acc + 128 denom floats per partial */

static __device__ __forceinline__ unsigned short f2bf(float f) {
  union { float f; unsigned int u; } a;
  a.f = f;
  unsigned int u = a.u;
  unsigned int lsb = (u >> 16) & 1u;
  u += 0x7fffu + lsb;  // RNE
  return (unsigned short)(u >> 16);
}

static __device__ __forceinline__ unsigned int cvtpk(float a, float b) {
  unsigned int r;
  asm("v_cvt_pk_bf16_f32 %0, %1, %2" : "=v"(r) : "v"(a), "v"(b));
  return r;
}

// cross-half (lane ^ 32) sum via v_permlane32_swap
static __device__ __forceinline__ float xsum32(float x) {
  u32x2 r = __builtin_amdgcn_permlane32_swap(__float_as_uint(x), __float_as_uint(x), false, false);
  return __uint_as_float(r[0]) + __uint_as_float(r[1]);
}

static __device__ __forceinline__ void gl_lds16(const void* g, void* l) {
  __builtin_amdgcn_global_load_lds(
      (const __attribute__((address_space(1))) unsigned int*)g,
      (__attribute__((address_space(3))) unsigned int*)l, 16, 0, 0);
}

// ---------------- fused prepass (one launch):
//   bid <  4096 : mask (Nk,Nq) -> bit-packed (Nk/32, Nq), inline dtype detect
//   4096..4607  : K transpose (B,E,N) f32 -> (B,N,E) bf16
//   4608..5119  : V convert   (B,E,N) f32 -> bf16 (layout kept)
__global__ __launch_bounds__(256) void k_pre(const float* __restrict__ Kf,
                                             const float* __restrict__ Vf,
                                             const unsigned char* __restrict__ Mp,
                                             unsigned short* __restrict__ Kb,
                                             unsigned short* __restrict__ Vb,
                                             unsigned int* __restrict__ Bits) {
  const int bid = blockIdx.x;
  const int t = threadIdx.x;
  if (bid < 4096) {
    __shared__ unsigned char Ts[64][80];
    __shared__ int sfl;
    const int q0 = (bid & 63) << 6;
    const int ky = bid >> 6;
    const int k0 = ky << 6;
    if (t == 0) sfl = 1;
    __syncthreads();
    {
      const unsigned int w0 = reinterpret_cast<const unsigned int*>(Mp)[t];
      if (!(w0 == 0u || w0 == 1u || w0 == 0x3F800000u)) sfl = 0;  // benign race
    }
    __syncthreads();
    const int wide = sfl;
    const int r = t >> 2, cs = t & 3;
    if (!wide) {
      int4 v = *reinterpret_cast<const int4*>(Mp + (size_t)(k0 + r) * NS + q0 + cs * 16);
      *reinterpret_cast<int4*>(&Ts[r][cs * 16]) = v;
    } else {
      const unsigned int* Mw =
          reinterpret_cast<const unsigned int*>(Mp) + (size_t)(k0 + r) * NS + q0 + cs * 16;
      unsigned char tmp[16];
#pragma unroll
      for (int j = 0; j < 16; ++j) tmp[j] = (unsigned char)(Mw[j] != 0u);
      *reinterpret_cast<int4*>(&Ts[r][cs * 16]) = *reinterpret_cast<const int4*>(tmp);
    }
    __syncthreads();
    const int w = t >> 6, lane = t & 63;
#pragma unroll
    for (int i = 0; i < 16; ++i) {
      const int q = (w << 4) + i;
      unsigned long long bm = __ballot(Ts[lane][q] != 0);
      if (lane == 0) {
        Bits[(size_t)(2 * ky) * NS + q0 + q] = (unsigned int)bm;
        Bits[(size_t)(2 * ky + 1) * NS + q0 + q] = (unsigned int)(bm >> 32);
      }
    }
  } else if (bid < 4608) {
    __shared__ float T[64][69];
    const int id = bid - 4096;
    const int b = id >> 6;
    const int n0 = (id & 63) << 6;
    const float* Xb = Kf + (size_t)b * EH * NS;
    unsigned short* Yb = Kb + (size_t)b * NS * EH;
    const int er = t >> 4;
    const int n4 = (t & 15) << 2;
#pragma unroll
    for (int p = 0; p < 4; ++p) {
      const int e = er + (p << 4);
      const float4 v = *reinterpret_cast<const float4*>(Xb + (size_t)e * NS + n0 + n4);
      T[e][n4] = v.x; T[e][n4 + 1] = v.y; T[e][n4 + 2] = v.z; T[e][n4 + 3] = v.w;
    }
    __syncthreads();
    const int n = t >> 2;
    const int e0 = (t & 3) << 4;
    u16x8 o0, o1;
#pragma unroll
    for (int j = 0; j < 8; ++j) o0[j] = f2bf(T[e0 + j][n]);
#pragma unroll
    for (int j = 0; j < 8; ++j) o1[j] = f2bf(T[e0 + 8 + j][n]);
    *reinterpret_cast<u16x8*>(Yb + (size_t)(n0 + n) * EH + e0) = o0;
    *reinterpret_cast<u16x8*>(Yb + (size_t)(n0 + n) * EH + e0 + 8) = o1;
  } else {
    const int id = bid - 4608;
    const size_t base = (size_t)id * 4096 + t * 4;
#pragma unroll
    for (int i = 0; i < 4; ++i) {
      const float4 v = *reinterpret_cast<const float4*>(Vf + base + i * 1024);
      u16x4 o;
      o[0] = f2bf(v.x); o[1] = f2bf(v.y); o[2] = f2bf(v.z); o[3] = f2bf(v.w);
      *reinterpret_cast<u16x4*>(Vb + base + i * 1024) = o;
    }
  }
}

// ---------------- fused flash attention: R6 dbuf loop x split-K x2 x 1024-thr
// grid 512: b = bid&7, qt = (bid>>3)&31, kh = bid>>8. 128 q/block, 2048 keys/block.
// 16 waves = wq4 x wk4. LDS 64KB (K dbuf 2x16K + V dbuf 2x16K). 8192 waves total.
__global__ __launch_bounds__(1024, 4) void k_attn8(const unsigned short* __restrict__ Kb,
                                                   const unsigned short* __restrict__ Vb,
                                                   const float* __restrict__ Qf,
                                                   const unsigned int* __restrict__ Bits,
                                                   float* __restrict__ Pw) {
  // pool: [0,16K) K b0 | [16K,32K) K b1 | [32K,48K) V b0 | [48K,64K) V b1
  // epilogue alias: M0 [4][3][16][66] f32 (50688 B) | Lml [4][3][64] @50688
  __shared__ __align__(16) char pool[65536];

  const int bid = blockIdx.x;
  const int b = bid & 7;              // batch -> XCD (L2 locality)
  const int qt = (bid >> 3) & 31;
  const int kh = bid >> 8;            // key half (0/1)
  const int q0 = qt << 7;             // 128 q per block
  const int t = threadIdx.x;
  const int w = t >> 6;
  const int wq = w & 3;               // 4 q sub-tiles of 32
  const int wk = w >> 2;              // 4 key splits of 32 (within supertile)
  const int l = t & 63;
  const int l32 = l & 31;
  const int hi = l >> 5;
  const int qrow = q0 + (wq << 5) + l32;

  // ---- Q fragments (B operand of S^T = K*Q), scale folded
  bf16x8 qf[4];
  {
    const float* qb = Qf + (size_t)b * EH * NS + qrow;
#pragma unroll
    for (int eb = 0; eb < 4; ++eb)
#pragma unroll
      for (int j = 0; j < 8; ++j)
        qf[eb][j] = (short)f2bf(qb[(size_t)(16 * eb + 8 * hi + j) * NS] * SCALE_L2E);
  }

  // ---- DMA sources (pre-swizzled global, linear LDS dest); 1 chunk each
  const char* kg = (const char*)(Kb + ((size_t)b * NS + (size_t)kh * 2048) * EH) +
                   (((size_t)t * 16) ^ (size_t)(((t >> 3) & 7) << 4));
  const char* vg = (const char*)(Vb + (size_t)b * EH * NS + (size_t)kh * 2048) +
                   (size_t)(t >> 4) * (NS * 2) +
                   (size_t)((((t & 15) << 4)) ^ (((t >> 4) & 15) << 4));

  // ---- LDS read offsets (same XOR involution)
  const int R = (wk << 5) + l32;  // key row in 128-key supertile
  int koff[4];
#pragma unroll
  for (int eb = 0; eb < 4; ++eb)
    koff[eb] = (R << 7) + (((eb << 5) + (hi << 4)) ^ ((R & 7) << 4));
  int voff[2][2];
#pragma unroll
  for (int vb = 0; vb < 2; ++vb)
#pragma unroll
    for (int kb = 0; kb < 2; ++kb) {
      const int e = (vb << 5) + l32;
      voff[vb][kb] = (e << 8) + (((wk << 6) + (kb << 5) + (hi << 4)) ^ ((e & 15) << 4));
    }

  const unsigned int* mp = Bits + ((size_t)(kh << 6) + wk) * NS + qrow;

  f32x16 acc0, acc1;
#pragma unroll
  for (int r = 0; r < 16; ++r) { acc0[r] = 0.f; acc1[r] = 0.f; }
  float l_r = 0.f;

  // ---- prologue: stage supertile 0
  gl_lds16(kg, pool + t * 16);
  gl_lds16(vg, pool + 32768 + t * 16);
  unsigned int mw = mp[0];
  __syncthreads();

  unsigned int mw_n = 0;
  for (int kt = 0; kt < 16; ++kt) {
    const int cur = kt & 1;
    // issue next-supertile DMA early (lands by this iteration's end barrier)
    if (kt < 15) {
      gl_lds16(kg + (size_t)(kt + 1) * 16384, pool + ((cur ^ 1) << 14) + t * 16);
      gl_lds16(vg + (size_t)(kt + 1) * 256, pool + 32768 + ((cur ^ 1) << 14) + t * 16);
      mw_n = mp[(size_t)(kt + 1) * 4 * NS];
    }

    const char* Kt = pool + (cur << 14);
    const char* Vt = pool + 32768 + (cur << 14);

    // ---- S^T init = mask (C-operand): masked entries start at -inf
    const unsigned int mwh = mw >> (hi << 2);
    f32x16 s;
#pragma unroll
    for (int r = 0; r < 16; ++r) {
      const int kl = (r & 3) + ((r >> 2) << 3);  // compile-time per r
      s[r] = __int_as_float(((int)(mwh << (31 - kl)) >> 31) & 0xFF800000);
    }

    // ---- S^T[k][q]
    const bf16x8 ka0 = *reinterpret_cast<const bf16x8*>(Kt + koff[0]);
    const bf16x8 ka1 = *reinterpret_cast<const bf16x8*>(Kt + koff[1]);
    const bf16x8 ka2 = *reinterpret_cast<const bf16x8*>(Kt + koff[2]);
    const bf16x8 ka3 = *reinterpret_cast<const bf16x8*>(Kt + koff[3]);
    __builtin_amdgcn_s_setprio(1);
    s = __builtin_amdgcn_mfma_f32_32x32x16_bf16(ka0, qf[0], s, 0, 0, 0);
    s = __builtin_amdgcn_mfma_f32_32x32x16_bf16(ka1, qf[1], s, 0, 0, 0);
    s = __builtin_amdgcn_mfma_f32_32x32x16_bf16(ka2, qf[2], s, 0, 0, 0);
    s = __builtin_amdgcn_mfma_f32_32x32x16_bf16(ka3, qf[3], s, 0, 0, 0);
    __builtin_amdgcn_s_setprio(0);

    // ---- p = 2^s (fixed-M; masked -> exp2(-inf)=0), deferred denom
#pragma unroll
    for (int r = 0; r < 16; ++r) s[r] = exp2f(s[r]);
    l_r += (((s[0] + s[1]) + (s[2] + s[3])) + ((s[4] + s[5]) + (s[6] + s[7]))) +
           (((s[8] + s[9]) + (s[10] + s[11])) + ((s[12] + s[13]) + (s[14] + s[15])));

    // ---- PV: cvt_pk -> permlane32_swap -> MFMAs
    const bf16x8 va00 = *reinterpret_cast<const bf16x8*>(Vt + voff[0][0]);
    const bf16x8 va01 = *reinterpret_cast<const bf16x8*>(Vt + voff[1][0]);
    const bf16x8 va10 = *reinterpret_cast<const bf16x8*>(Vt + voff[0][1]);
    const bf16x8 va11 = *reinterpret_cast<const bf16x8*>(Vt + voff[1][1]);
#pragma unroll
    for (int kb = 0; kb < 2; ++kb) {
      const unsigned int wA0 = cvtpk(s[8 * kb + 0], s[8 * kb + 1]);
      const unsigned int wA1 = cvtpk(s[8 * kb + 2], s[8 * kb + 3]);
      const unsigned int wB0 = cvtpk(s[8 * kb + 4], s[8 * kb + 5]);
      const unsigned int wB1 = cvtpk(s[8 * kb + 6], s[8 * kb + 7]);
      const u32x2 p02 = __builtin_amdgcn_permlane32_swap(wA0, wB0, false, false);
      const u32x2 p13 = __builtin_amdgcn_permlane32_swap(wA1, wB1, false, false);
      u32x4 pw;
      pw[0] = p02[0];
      pw[1] = p13[0];
      pw[2] = p02[1];
      pw[3] = p13[1];
      const bf16x8 pfrag = __builtin_bit_cast(bf16x8, pw);
      __builtin_amdgcn_s_setprio(1);
      acc0 = __builtin_amdgcn_mfma_f32_32x32x16_bf16(kb ? va10 : va00, pfrag, acc0, 0, 0, 0);
      acc1 = __builtin_amdgcn_mfma_f32_32x32x16_bf16(kb ? va11 : va01, pfrag, acc1, 0, 0, 0);
      __builtin_amdgcn_s_setprio(0);
    }

    mw = mw_n;
    __syncthreads();  // drains DMA; next buffer ready
  }

  // ---- finalize denom across lane halves (deferred from loop)
  l_r = xsum32(l_r);

  // ---- in-block 4-way wk merge (two phases), write unnormalized partial
  float* M0 = reinterpret_cast<float*>(pool);           // [4][3][16][66]
  float* Lml = reinterpret_cast<float*>(pool + 50688);  // [4][3][64]
  float* pp = Pw + ((size_t)(((qt << 3) + b) << 1) + kh) * PBLK;

  // phase A: acc0 + denom
  if (wk > 0) {
    float* A = M0 + (size_t)(wq * 3 + (wk - 1)) * 16 * 66;
#pragma unroll
    for (int r = 0; r < 16; ++r) A[r * 66 + l] = acc0[r];
    Lml[(wq * 3 + (wk - 1)) * 64 + l] = l_r;
  }
  __syncthreads();
  if (wk == 0) {
    float L = l_r;
#pragma unroll
    for (int s0 = 0; s0 < 3; ++s0) L += Lml[(wq * 3 + s0) * 64 + l];
    if (hi == 0) pp[8192 + (wq << 5) + l32] = L;
#pragma unroll
    for (int r = 0; r < 16; ++r) {
      const int v0 = (r & 3) + ((r >> 2) << 3) + (hi << 2);
      float o = acc0[r];
#pragma unroll
      for (int s0 = 0; s0 < 3; ++s0) o += M0[((size_t)(wq * 3 + s0) * 16 + r) * 66 + l];
      pp[v0 * 128 + (wq << 5) + l32] = o;
    }
  }
  __syncthreads();
  // phase B: acc1
  if (wk > 0) {
    float* A = M0 + (size_t)(wq * 3 + (wk - 1)) * 16 * 66;
#pragma unroll
    for (int r = 0; r < 16; ++r) A[r * 66 + l] = acc1[r];
  }
  __syncthreads();
  if (wk == 0) {
#pragma unroll
    for (int r = 0; r < 16; ++r) {
      const int v0 = (r & 3) + ((r >> 2) << 3) + (hi << 2) + 32;
      float o = acc1[r];
#pragma unroll
      for (int s0 = 0; s0 < 3; ++s0) o += M0[((size_t)(wq * 3 + s0) * 16 + r) * 66 + l];
      pp[v0 * 128 + (wq << 5) + l32] = o;
    }
  }
}

// ---------------- merge the two key-halves and normalize
// grid 256: b = bid&7, qt = bid>>3. Tile: 64 v x 128 q.
__global__ __launch_bounds__(256) void k_merge(const float* __restrict__ Pw,
                                               float* __restrict__ Out) {
  __shared__ float inv[128];
  const int bid = blockIdx.x;
  const int b = bid & 7;
  const int qt = bid >> 3;
  const float* A = Pw + ((size_t)(((qt << 3) + b)) << 1) * PBLK;
  const float* B = A + PBLK;
  const int t = threadIdx.x;
  if (t < 128) inv[t] = 1.0f / (A[8192 + t] + B[8192 + t]);
  __syncthreads();
  const int v = t >> 2;
  const int qc = (t & 3) << 5;
  const float* ar = A + v * 128 + qc;
  const float* br = B + v * 128 + qc;
  float* ob = Out + ((size_t)b * EH + v) * NS + (qt << 7) + qc;
#pragma unroll
  for (int j = 0; j < 8; ++j) {
    const float4 av = *reinterpret_cast<const float4*>(ar + 4 * j);
    const float4 bv = *reinterpret_cast<const float4*>(br + 4 * j);
    const float4 iv = *reinterpret_cast<const float4*>(&inv[qc + 4 * j]);
    float4 o;
    o.x = (av.x + bv.x) * iv.x;
    o.y = (av.y + bv.y) * iv.y;
    o.z = (av.z + bv.z) * iv.z;
    o.w = (av.w + bv.w) * iv.w;
    *reinterpret_cast<float4*>(ob + 4 * j) = o;
  }
}

extern "C" void kernel_launch(void* const* d_in, const int* in_sizes, int n_in,
                              void* d_out, int out_size, void* d_ws, size_t ws_size,
                              hipStream_t stream) {
  const float* Qf = (const float*)d_in[0];
  const float* Kf = (const float*)d_in[1];
  const float* Vf = (const float*)d_in[2];
  const unsigned char* Mp = (const unsigned char*)d_in[3];
  float* Out = (float*)d_out;

  unsigned short* Kb = (unsigned short*)d_ws;                       // 4 MB
  unsigned short* Vb = Kb + (size_t)NB * NS * EH;                   // 4 MB
  unsigned int* Bits = (unsigned int*)(Vb + (size_t)NB * NS * EH);  // 2 MB
  float* Pw = (float*)((char*)d_ws + 10 * 1024 * 1024 + 1024);      // ~17 MB partials

  k_pre<<<dim3(5120), 256, 0, stream>>>(Kf, Vf, Mp, Kb, Vb, Bits);
  k_attn8<<<dim3(512), 1024, 0, stream>>>(Kb, Vb, Qf, Bits, Pw);
  k_merge<<<dim3(256), 256, 0, stream>>>(Pw, Out);
}